// Round 3
// baseline (306.866 us; speedup 1.0000x reference)
//
#include <hip/hip_runtime.h>
#include <hip/hip_bf16.h>

#define C_DIM 64
#define N_TOK 4608
#define NBLK  72       // proj blocks per batch (64 tokens each)
#define B_SZ  2
#define M64BLKS 72     // attn m-blocks per batch (64 m-tokens each)
#define NSEG  8        // n-segments == waves per attn block
#define SEGLEN (N_TOK / NSEG)   // 576
#define NT64  (SEGLEN / 64)     // 9 n-tiles of 64 tokens per wave
#define KTILES 288     // N_TOK/16 swizzled 16-row K/Q tiles per batch
#define VTILES 72      // N_TOK/64 swizzled 64-token V tiles per batch
#define OSTR  68       // o_lds padded stride (floats)
#define REPS  16       // amplification factor (instrumentation round)

typedef __bf16 bf16x8 __attribute__((ext_vector_type(8)));
typedef float  f32x4  __attribute__((ext_vector_type(4)));

// ---------------------------------------------------------------------------
// Round 14: INSTRUMENTATION. R12 (DMA staging) and R13 (2x occupancy) were
// both ~null vs R11 => attn is a SMALL fraction of dur_us and has never been
// visible in the top-5 counter table (fills at ~42us dominate). This round
// restores the best attn (R11) and amplifies its main loop REPS=16x
// (re-zeroed accumulators, start-tile rotated per rep, outputs kept live via
// empty asm per DCE rule) so attn MUST appear in the counter table with its
// true MfmaUtil/VALUBusy/Occupancy. True attn time = (dur - 93.2)/15.
// Output is bit-equivalent up to fp32 sum order (tolerance 3.9e-3 >> that).
// proj unchanged.
// ---------------------------------------------------------------------------

__device__ __forceinline__ void gemm_tile(
    const __hip_bfloat16* wmat, const bf16x8 bin[2], const float* bias,
    int col, int quad, f32x4 acc[4])
{
    #pragma unroll
    for (int ot = 0; ot < 4; ot++) {
        f32x4 a = (f32x4){0.f, 0.f, 0.f, 0.f};
        #pragma unroll
        for (int kh = 0; kh < 2; kh++) {
            bf16x8 wf = *(const bf16x8*)(wmat + (ot * 16 + col) * 72 +
                                         kh * 32 + quad * 8);
            a = __builtin_amdgcn_mfma_f32_16x16x32_bf16(wf, bin[kh], a, 0, 0, 0);
        }
        float4 b4 = *(const float4*)(bias + ot * 16 + quad * 4);
        a[0] += b4.x; a[1] += b4.y; a[2] += b4.z; a[3] += b4.w;
        acc[ot] = a;
    }
}

__global__ __launch_bounds__(256) void proj_kernel(
    const float* __restrict__ x,  const float* __restrict__ h,
    const float* __restrict__ Wq, const float* __restrict__ bq,
    const float* __restrict__ Wk, const float* __restrict__ bk,
    const float* __restrict__ Wv, const float* __restrict__ bv,
    __hip_bfloat16* __restrict__ qS, __hip_bfloat16* __restrict__ kS,
    __hip_bfloat16* __restrict__ vS)
{
    __shared__ __hip_bfloat16 wl[3 * 64 * 72];
    __shared__ __hip_bfloat16 xt[64 * 72];
    __shared__ __hip_bfloat16 ht[64 * 72];
    __shared__ __hip_bfloat16 vl[64 * 72];

    const int b  = blockIdx.x / NBLK;
    const int n0 = (blockIdx.x % NBLK) * 64;
    const int t  = threadIdx.x;

    #pragma unroll
    for (int mat = 0; mat < 3; mat++) {
        const float* W = (mat == 0) ? Wq : ((mat == 1) ? Wk : Wv);
        __hip_bfloat16* wd = wl + mat * (64 * 72);
        #pragma unroll
        for (int i = 0; i < 4; i++) {
            const int ch = i * 256 + t;
            const int o = ch >> 4, c0 = (ch & 15) * 4;
            float4 w4 = *(const float4*)(W + ch * 4);
            union { __hip_bfloat16 e[4]; uint2 v; } pk;
            pk.e[0] = __float2bfloat16(w4.x); pk.e[1] = __float2bfloat16(w4.y);
            pk.e[2] = __float2bfloat16(w4.z); pk.e[3] = __float2bfloat16(w4.w);
            *(uint2*)(wd + o * 72 + c0) = pk.v;
        }
    }
    #pragma unroll
    for (int i = 0; i < 4; i++) {
        const int ch = i * 256 + t;
        const int c = ch >> 4, n4 = (ch & 15) * 4;
        float4 x4 = *(const float4*)(x + (size_t)(b * C_DIM + c) * N_TOK + n0 + n4);
        float4 h4 = *(const float4*)(h + (size_t)(b * C_DIM + c) * N_TOK + n0 + n4);
        xt[(n4 + 0) * 72 + c] = __float2bfloat16(x4.x);
        xt[(n4 + 1) * 72 + c] = __float2bfloat16(x4.y);
        xt[(n4 + 2) * 72 + c] = __float2bfloat16(x4.z);
        xt[(n4 + 3) * 72 + c] = __float2bfloat16(x4.w);
        ht[(n4 + 0) * 72 + c] = __float2bfloat16(h4.x);
        ht[(n4 + 1) * 72 + c] = __float2bfloat16(h4.y);
        ht[(n4 + 2) * 72 + c] = __float2bfloat16(h4.z);
        ht[(n4 + 3) * 72 + c] = __float2bfloat16(h4.w);
    }
    __syncthreads();

    const int wave = t >> 6, lane = t & 63;
    const int col = lane & 15, quad = lane >> 4;

    bf16x8 xb[2], hb[2];
    #pragma unroll
    for (int kh = 0; kh < 2; kh++) {
        xb[kh] = *(const bf16x8*)(xt + (wave * 16 + col) * 72 + kh * 32 + quad * 8);
        hb[kh] = *(const bf16x8*)(ht + (wave * 16 + col) * 72 + kh * 32 + quad * 8);
    }

    f32x4 acc[4];

    gemm_tile(wl + 0 * (64 * 72), xb, bq, col, quad, acc);
    {
        const size_t tile16 = (size_t)b * KTILES + (n0 >> 4) + wave;
        const float SC = 0.125f * 1.44269504088896f;
        #pragma unroll
        for (int ot = 0; ot < 4; ot++) {
            union { __hip_bfloat16 e[4]; uint2 v; } pk;
            #pragma unroll
            for (int r = 0; r < 4; r++) pk.e[r] = __float2bfloat16(acc[ot][r] * SC);
            *(uint2*)(qS + (tile16 << 10) + (ot >> 1) * 512 +
                      ((ot * 2 + (quad >> 1)) & 3) * 128 + col * 8 +
                      (quad & 1) * 4) = pk.v;
        }
    }

    gemm_tile(wl + 1 * (64 * 72), hb, bk, col, quad, acc);
    {
        const int t_l = (wave >> 1) * 2 + ((col >> 2) & 1);
        const int row = ((wave * 2 + (col >> 3)) & 3) * 4 + (col & 3);
        const size_t tile16 = (size_t)b * KTILES + (n0 >> 4) + t_l;
        #pragma unroll
        for (int ot = 0; ot < 4; ot++) {
            union { __hip_bfloat16 e[4]; uint2 v; } pk;
            #pragma unroll
            for (int r = 0; r < 4; r++) pk.e[r] = __float2bfloat16(acc[ot][r]);
            *(uint2*)(kS + (tile16 << 10) + (ot >> 1) * 512 +
                      ((ot * 2 + (quad >> 1)) & 3) * 128 + row * 8 +
                      (quad & 1) * 4) = pk.v;
        }
    }

    gemm_tile(wl + 2 * (64 * 72), hb, bv, col, quad, acc);
    #pragma unroll
    for (int ot = 0; ot < 4; ot++)
        #pragma unroll
        for (int r = 0; r < 4; r++)
            vl[(ot * 16 + quad * 4 + r) * 72 + wave * 16 + col] =
                __float2bfloat16(acc[ot][r]);
    __syncthreads();
    {
        const size_t vbase = ((size_t)(b * VTILES) + (n0 >> 6)) << 12;
        #pragma unroll
        for (int rep = 0; rep < 2; rep++) {
            const int ch = rep * 256 + t;
            const int cc = ch >> 7, hf = (ch >> 6) & 1;
            const int qd = (ch >> 4) & 3, c2 = ch & 15;
            *(uint4*)(vS + vbase + (size_t)ch * 8) =
                *(const uint4*)(vl + (cc * 16 + c2) * 72 + hf * 32 + qd * 8);
        }
    }
}

// ---------------------------------------------------------------------------
// Flash attention, R11 structure, REPS-amplified for profiling. 8 waves;
// each wave owns all 4 m-subtiles and 1/8 of n (576 tokens, 9 x 64-token
// tiles). Barrier-free inner loop. grid = B*72 blocks of 512.
// ---------------------------------------------------------------------------
__global__ __launch_bounds__(512) void attn_kernel(
    const __hip_bfloat16* __restrict__ qS,
    const __hip_bfloat16* __restrict__ kS,
    const __hip_bfloat16* __restrict__ vS,
    float* __restrict__ out)
{
    __shared__ float o_lds[NSEG * 16 * OSTR];
    __shared__ float lstat[NSEG][64];

    const int b    = blockIdx.x / M64BLKS;
    const int mblk = blockIdx.x % M64BLKS;
    const int wave = threadIdx.x >> 6;
    const int lane = threadIdx.x & 63;
    const int col  = lane & 15;
    const int quad = lane >> 4;
    const int m0   = mblk * 64;

    // loop-invariant Q fragments for the 4 m-subtiles (contiguous 1KB loads)
    const __hip_bfloat16* qp =
        qS + (((size_t)b * KTILES + (m0 >> 4)) << 10) + lane * 8;
    bf16x8 qa[4][2];
    #pragma unroll
    for (int ms = 0; ms < 4; ms++) {
        qa[ms][0] = *(const bf16x8*)(qp + ms * 1024);
        qa[ms][1] = *(const bf16x8*)(qp + ms * 1024 + 512);
    }

    f32x4 accO[4][4];
    float rsum[4];
    const int nbeg = wave * SEGLEN;

    #pragma unroll 1
    for (int rep = 0; rep < REPS; rep++) {
        #pragma unroll
        for (int ms = 0; ms < 4; ms++) {
            #pragma unroll
            for (int cc = 0; cc < 4; cc++)
                accO[ms][cc] = (f32x4){0.f, 0.f, 0.f, 0.f};
            rsum[ms] = 0.f;
        }

        int rep9 = rep;                       // rep % NT64 (REPS < 2*NT64)
        if (rep9 >= NT64) rep9 -= NT64;

        #pragma unroll 1
        for (int ti = 0; ti < NT64; ti++) {
            int tt = ti + rep9;               // rotated tile order per rep:
            if (tt >= NT64) tt -= NT64;       // same set, non-identical reps
            const int n0 = nbeg + tt * 64;

            // ---- K/V fragment loads (shared by all 4 m-subtiles) ----
            const __hip_bfloat16* kt =
                kS + (((size_t)b * KTILES + (n0 >> 4)) << 10) + lane * 8;
            bf16x8 ka[8];
            #pragma unroll
            for (int j = 0; j < 4; j++) {
                ka[2 * j]     = *(const bf16x8*)(kt + (j << 10));
                ka[2 * j + 1] = *(const bf16x8*)(kt + (j << 10) + 512);
            }
            const __hip_bfloat16* vt =
                vS + ((((size_t)b * VTILES) + (n0 >> 6)) << 12) + lane * 8;
            bf16x8 va[8];
            #pragma unroll
            for (int cc = 0; cc < 4; cc++) {
                va[2 * cc]     = *(const bf16x8*)(vt + cc * 1024);
                va[2 * cc + 1] = *(const bf16x8*)(vt + cc * 1024 + 512);
            }

            // ---- per m-subtile: S^T -> exp2 -> PV (s regs transient) ----
            #pragma unroll
            for (int ms = 0; ms < 4; ms++) {
                f32x4 s[4];
                #pragma unroll
                for (int j = 0; j < 4; j++) {
                    s[j] = __builtin_amdgcn_mfma_f32_16x16x32_bf16(
                               ka[2 * j], qa[ms][0],
                               (f32x4){0.f, 0.f, 0.f, 0.f}, 0, 0, 0);
                    s[j] = __builtin_amdgcn_mfma_f32_16x16x32_bf16(
                               ka[2 * j + 1], qa[ms][1], s[j], 0, 0, 0);
                }
                union { __hip_bfloat16 e[8]; bf16x8 v; } p0, p1;
                float ps = 0.f;
                #pragma unroll
                for (int j = 0; j < 2; j++)
                    #pragma unroll
                    for (int r = 0; r < 4; r++) {
                        float e0 = __builtin_amdgcn_exp2f(s[j][r]);
                        float e1 = __builtin_amdgcn_exp2f(s[2 + j][r]);
                        ps += e0 + e1;
                        p0.e[j * 4 + r] = __float2bfloat16(e0);
                        p1.e[j * 4 + r] = __float2bfloat16(e1);
                    }
                rsum[ms] += ps;
                #pragma unroll
                for (int cc = 0; cc < 4; cc++) {
                    accO[ms][cc] = __builtin_amdgcn_mfma_f32_16x16x32_bf16(
                                       va[2 * cc], p0.v, accO[ms][cc], 0, 0, 0);
                    accO[ms][cc] = __builtin_amdgcn_mfma_f32_16x16x32_bf16(
                                       va[2 * cc + 1], p1.v, accO[ms][cc], 0, 0, 0);
                }
            }
        }

        // keep every rep's results live (anti-DCE, rule #17): consume the
        // tail of each accumulator chain + each rsum. Reads only; the final
        // rep's values flow to the combine unchanged.
        #pragma unroll
        for (int ms = 0; ms < 4; ms++) {
            #pragma unroll
            for (int cc = 0; cc < 4; cc++)
                asm volatile("" :: "v"(accO[ms][cc][0]));
            asm volatile("" :: "v"(rsum[ms]));
        }
    }

    // ---- finalize per-wave stats ----
    #pragma unroll
    for (int ms = 0; ms < 4; ms++) {
        rsum[ms] += __shfl_xor(rsum[ms], 16);
        rsum[ms] += __shfl_xor(rsum[ms], 32);
    }
    if (quad == 0) {
        #pragma unroll
        for (int ms = 0; ms < 4; ms++) lstat[wave][ms * 16 + col] = rsum[ms];
    }

    // ---- four-phase combine over 8 segments (o_lds reused per phase) ----
    #pragma unroll
    for (int phase = 0; phase < 4; phase++) {
        #pragma unroll
        for (int cc = 0; cc < 4; cc++)
            *(f32x4*)(o_lds + (wave * 16 + col) * OSTR + cc * 16 + quad * 4) =
                accO[phase][cc];
        __syncthreads();
        if (threadIdx.x < 256) {
            const int m  = threadIdx.x & 15;
            const int cq = threadIdx.x >> 4;
            const int mi = phase * 16 + m;
            float lsum = 0.f;
            f32x4 oacc = (f32x4){0.f, 0.f, 0.f, 0.f};
            #pragma unroll
            for (int sgm = 0; sgm < NSEG; sgm++) {
                lsum += lstat[sgm][mi];
                oacc += *(const f32x4*)(o_lds + (sgm * 16 + m) * OSTR + cq * 4);
            }
            const float inv = 1.0f / lsum;
            #pragma unroll
            for (int r = 0; r < 4; r++) {
                const int c = cq * 4 + r;
                out[(size_t)(b * C_DIM + c) * N_TOK + m0 + phase * 16 + m] =
                    oacc[r] * inv;
            }
        }
        __syncthreads();
    }
}

extern "C" void kernel_launch(void* const* d_in, const int* in_sizes, int n_in,
                              void* d_out, int out_size, void* d_ws, size_t ws_size,
                              hipStream_t stream) {
    const float* x  = (const float*)d_in[0];
    const float* h  = (const float*)d_in[1];
    const float* Wq = (const float*)d_in[2];
    const float* bq = (const float*)d_in[3];
    const float* Wk = (const float*)d_in[4];
    const float* bk = (const float*)d_in[5];
    const float* Wv = (const float*)d_in[6];
    const float* bv = (const float*)d_in[7];
    float* out = (float*)d_out;

    const size_t elems = (size_t)B_SZ * N_TOK * C_DIM;   // 589824
    __hip_bfloat16* qS = (__hip_bfloat16*)d_ws;
    __hip_bfloat16* kS = qS + elems;
    __hip_bfloat16* vS = kS + elems;

    proj_kernel<<<B_SZ * NBLK, 256, 0, stream>>>(x, h, Wq, bq, Wk, bk, Wv, bv,
                                                 qS, kS, vS);
    attn_kernel<<<B_SZ * M64BLKS, 512, 0, stream>>>(qS, kS, vS, out);
}

// Round 4
// 92.476 us; speedup vs baseline: 3.3183x; 3.3183x over previous
//
#include <hip/hip_runtime.h>
#include <hip/hip_bf16.h>

#define C_DIM 64
#define N_TOK 4608
#define NBLK  72       // proj blocks per batch (64 tokens each)
#define B_SZ  2
#define M128BLKS 36    // attn m-blocks per batch (128 m-tokens each)
#define NSPLIT 3       // n-splits across blocks (1536 tokens each)
#define NSEG  4        // n-segments per m-group inside a block (4 waves)
#define SEGLEN 384     // 1536 / NSEG tokens per wave
#define NT    6        // 384/64 tiles per wave
#define KTILES 288     // N_TOK/16 swizzled 16-row K/Q tiles per batch
#define VTILES 72      // N_TOK/64 swizzled 64-token V tiles per batch
#define OSTR  68       // o_lds padded stride (floats)

typedef __bf16 bf16x8 __attribute__((ext_vector_type(8)));
typedef float  f32x4  __attribute__((ext_vector_type(4)));

// ---------------------------------------------------------------------------
// Round 15: cold-read partitioning. R14 amplification measured attn: warm
// steady-state 14.25 us/pass but real single-shot ~46 us => ~32 us is
// FIRST-TOUCH K/V read cost at ~26 GB/s/CU (per-CU miss-service limit; HBM
// ~0, conflicts ~0). R12 (prefetch) and R13 (more waves) were null because
// neither reduces bytes-per-CU. This round: M=128 x n-third blocks ->
// 216 blocks (84% of chip), 0.39 MB single-touch per block (3x less).
// Blocks write unnormalized partials (O,l) in [b][c][m] layout; norm_kernel
// sums 3 partials + divides. Per-wave inner loop byte-identical to R11.
// proj unchanged (4.8 us, R9).
// ---------------------------------------------------------------------------

__device__ __forceinline__ void gemm_tile(
    const __hip_bfloat16* wmat, const bf16x8 bin[2], const float* bias,
    int col, int quad, f32x4 acc[4])
{
    #pragma unroll
    for (int ot = 0; ot < 4; ot++) {
        f32x4 a = (f32x4){0.f, 0.f, 0.f, 0.f};
        #pragma unroll
        for (int kh = 0; kh < 2; kh++) {
            bf16x8 wf = *(const bf16x8*)(wmat + (ot * 16 + col) * 72 +
                                         kh * 32 + quad * 8);
            a = __builtin_amdgcn_mfma_f32_16x16x32_bf16(wf, bin[kh], a, 0, 0, 0);
        }
        float4 b4 = *(const float4*)(bias + ot * 16 + quad * 4);
        a[0] += b4.x; a[1] += b4.y; a[2] += b4.z; a[3] += b4.w;
        acc[ot] = a;
    }
}

__global__ __launch_bounds__(256) void proj_kernel(
    const float* __restrict__ x,  const float* __restrict__ h,
    const float* __restrict__ Wq, const float* __restrict__ bq,
    const float* __restrict__ Wk, const float* __restrict__ bk,
    const float* __restrict__ Wv, const float* __restrict__ bv,
    __hip_bfloat16* __restrict__ qS, __hip_bfloat16* __restrict__ kS,
    __hip_bfloat16* __restrict__ vS)
{
    __shared__ __hip_bfloat16 wl[3 * 64 * 72];
    __shared__ __hip_bfloat16 xt[64 * 72];
    __shared__ __hip_bfloat16 ht[64 * 72];
    __shared__ __hip_bfloat16 vl[64 * 72];

    const int b  = blockIdx.x / NBLK;
    const int n0 = (blockIdx.x % NBLK) * 64;
    const int t  = threadIdx.x;

    #pragma unroll
    for (int mat = 0; mat < 3; mat++) {
        const float* W = (mat == 0) ? Wq : ((mat == 1) ? Wk : Wv);
        __hip_bfloat16* wd = wl + mat * (64 * 72);
        #pragma unroll
        for (int i = 0; i < 4; i++) {
            const int ch = i * 256 + t;
            const int o = ch >> 4, c0 = (ch & 15) * 4;
            float4 w4 = *(const float4*)(W + ch * 4);
            union { __hip_bfloat16 e[4]; uint2 v; } pk;
            pk.e[0] = __float2bfloat16(w4.x); pk.e[1] = __float2bfloat16(w4.y);
            pk.e[2] = __float2bfloat16(w4.z); pk.e[3] = __float2bfloat16(w4.w);
            *(uint2*)(wd + o * 72 + c0) = pk.v;
        }
    }
    #pragma unroll
    for (int i = 0; i < 4; i++) {
        const int ch = i * 256 + t;
        const int c = ch >> 4, n4 = (ch & 15) * 4;
        float4 x4 = *(const float4*)(x + (size_t)(b * C_DIM + c) * N_TOK + n0 + n4);
        float4 h4 = *(const float4*)(h + (size_t)(b * C_DIM + c) * N_TOK + n0 + n4);
        xt[(n4 + 0) * 72 + c] = __float2bfloat16(x4.x);
        xt[(n4 + 1) * 72 + c] = __float2bfloat16(x4.y);
        xt[(n4 + 2) * 72 + c] = __float2bfloat16(x4.z);
        xt[(n4 + 3) * 72 + c] = __float2bfloat16(x4.w);
        ht[(n4 + 0) * 72 + c] = __float2bfloat16(h4.x);
        ht[(n4 + 1) * 72 + c] = __float2bfloat16(h4.y);
        ht[(n4 + 2) * 72 + c] = __float2bfloat16(h4.z);
        ht[(n4 + 3) * 72 + c] = __float2bfloat16(h4.w);
    }
    __syncthreads();

    const int wave = t >> 6, lane = t & 63;
    const int col = lane & 15, quad = lane >> 4;

    bf16x8 xb[2], hb[2];
    #pragma unroll
    for (int kh = 0; kh < 2; kh++) {
        xb[kh] = *(const bf16x8*)(xt + (wave * 16 + col) * 72 + kh * 32 + quad * 8);
        hb[kh] = *(const bf16x8*)(ht + (wave * 16 + col) * 72 + kh * 32 + quad * 8);
    }

    f32x4 acc[4];

    gemm_tile(wl + 0 * (64 * 72), xb, bq, col, quad, acc);
    {
        const size_t tile16 = (size_t)b * KTILES + (n0 >> 4) + wave;
        const float SC = 0.125f * 1.44269504088896f;
        #pragma unroll
        for (int ot = 0; ot < 4; ot++) {
            union { __hip_bfloat16 e[4]; uint2 v; } pk;
            #pragma unroll
            for (int r = 0; r < 4; r++) pk.e[r] = __float2bfloat16(acc[ot][r] * SC);
            *(uint2*)(qS + (tile16 << 10) + (ot >> 1) * 512 +
                      ((ot * 2 + (quad >> 1)) & 3) * 128 + col * 8 +
                      (quad & 1) * 4) = pk.v;
        }
    }

    gemm_tile(wl + 1 * (64 * 72), hb, bk, col, quad, acc);
    {
        const int t_l = (wave >> 1) * 2 + ((col >> 2) & 1);
        const int row = ((wave * 2 + (col >> 3)) & 3) * 4 + (col & 3);
        const size_t tile16 = (size_t)b * KTILES + (n0 >> 4) + t_l;
        #pragma unroll
        for (int ot = 0; ot < 4; ot++) {
            union { __hip_bfloat16 e[4]; uint2 v; } pk;
            #pragma unroll
            for (int r = 0; r < 4; r++) pk.e[r] = __float2bfloat16(acc[ot][r]);
            *(uint2*)(kS + (tile16 << 10) + (ot >> 1) * 512 +
                      ((ot * 2 + (quad >> 1)) & 3) * 128 + row * 8 +
                      (quad & 1) * 4) = pk.v;
        }
    }

    gemm_tile(wl + 2 * (64 * 72), hb, bv, col, quad, acc);
    #pragma unroll
    for (int ot = 0; ot < 4; ot++)
        #pragma unroll
        for (int r = 0; r < 4; r++)
            vl[(ot * 16 + quad * 4 + r) * 72 + wave * 16 + col] =
                __float2bfloat16(acc[ot][r]);
    __syncthreads();
    {
        const size_t vbase = ((size_t)(b * VTILES) + (n0 >> 6)) << 12;
        #pragma unroll
        for (int rep = 0; rep < 2; rep++) {
            const int ch = rep * 256 + t;
            const int cc = ch >> 7, hf = (ch >> 6) & 1;
            const int qd = (ch >> 4) & 3, c2 = ch & 15;
            *(uint4*)(vS + vbase + (size_t)ch * 8) =
                *(const uint4*)(vl + (cc * 16 + c2) * 72 + hf * 32 + qd * 8);
        }
    }
}

// ---------------------------------------------------------------------------
// Flash attention partials: grid = B * 36 * 3 = 216 blocks of 512.
// Block (b, mblk, ns): rows [mblk*128, +128), tokens [ns*1536, +1536).
// 8 waves = (mg 0/1: 64-row half) x (seg 0..3: 384-token quarter).
// Per-wave inner loop identical to R11 (6 tiles of 64 tokens).
// Emits unnormalized O-partials ([b][c][m] layout, f32) + l-partials.
// ---------------------------------------------------------------------------
__global__ __launch_bounds__(512) void attn_kernel(
    const __hip_bfloat16* __restrict__ qS,
    const __hip_bfloat16* __restrict__ kS,
    const __hip_bfloat16* __restrict__ vS,
    float* __restrict__ Pb, float* __restrict__ Lb)
{
    __shared__ float o_lds[2][NSEG][16][OSTR];   // 34.8 KB
    __shared__ float lstat[2][NSEG][64];         // 2 KB

    const int idx  = blockIdx.x;
    const int b    = idx / (M128BLKS * NSPLIT);
    const int rem  = idx % (M128BLKS * NSPLIT);
    const int mblk = rem / NSPLIT;
    const int ns   = rem % NSPLIT;
    const int wave = threadIdx.x >> 6;
    const int lane = threadIdx.x & 63;
    const int col  = lane & 15;
    const int quad = lane >> 4;
    const int mg   = wave >> 2;      // 64-row half
    const int seg  = wave & 3;       // 384-token quarter
    const int m0   = mblk * 128 + mg * 64;

    float* Pns = Pb + (size_t)ns * (B_SZ * C_DIM * N_TOK);
    float* Lns = Lb + (size_t)ns * (B_SZ * N_TOK);

    // loop-invariant Q fragments for this wave's 4 m-subtiles
    const __hip_bfloat16* qp =
        qS + (((size_t)b * KTILES + (m0 >> 4)) << 10) + lane * 8;
    bf16x8 qa[4][2];
    #pragma unroll
    for (int ms = 0; ms < 4; ms++) {
        qa[ms][0] = *(const bf16x8*)(qp + ms * 1024);
        qa[ms][1] = *(const bf16x8*)(qp + ms * 1024 + 512);
    }

    f32x4 accO[4][4];
    #pragma unroll
    for (int ms = 0; ms < 4; ms++)
        #pragma unroll
        for (int cc = 0; cc < 4; cc++)
            accO[ms][cc] = (f32x4){0.f, 0.f, 0.f, 0.f};
    float rsum[4] = {0.f, 0.f, 0.f, 0.f};

    const int nbeg = ns * (NSEG * SEGLEN) + seg * SEGLEN;

    #pragma unroll 1
    for (int t = 0; t < NT; t++) {
        const int n0 = nbeg + t * 64;
        // ---- K/V fragment loads (shared by all 4 m-subtiles) ----
        const __hip_bfloat16* kt =
            kS + (((size_t)b * KTILES + (n0 >> 4)) << 10) + lane * 8;
        bf16x8 ka[8];
        #pragma unroll
        for (int j = 0; j < 4; j++) {
            ka[2 * j]     = *(const bf16x8*)(kt + (j << 10));
            ka[2 * j + 1] = *(const bf16x8*)(kt + (j << 10) + 512);
        }
        const __hip_bfloat16* vt =
            vS + ((((size_t)b * VTILES) + (n0 >> 6)) << 12) + lane * 8;
        bf16x8 va[8];
        #pragma unroll
        for (int cc = 0; cc < 4; cc++) {
            va[2 * cc]     = *(const bf16x8*)(vt + cc * 1024);
            va[2 * cc + 1] = *(const bf16x8*)(vt + cc * 1024 + 512);
        }

        // ---- per m-subtile: S^T -> exp2 -> PV (s regs transient) ----
        #pragma unroll
        for (int ms = 0; ms < 4; ms++) {
            f32x4 s[4];
            #pragma unroll
            for (int j = 0; j < 4; j++) {
                s[j] = __builtin_amdgcn_mfma_f32_16x16x32_bf16(
                           ka[2 * j], qa[ms][0],
                           (f32x4){0.f, 0.f, 0.f, 0.f}, 0, 0, 0);
                s[j] = __builtin_amdgcn_mfma_f32_16x16x32_bf16(
                           ka[2 * j + 1], qa[ms][1], s[j], 0, 0, 0);
            }
            union { __hip_bfloat16 e[8]; bf16x8 v; } p0, p1;
            float ps = 0.f;
            #pragma unroll
            for (int j = 0; j < 2; j++)
                #pragma unroll
                for (int r = 0; r < 4; r++) {
                    float e0 = __builtin_amdgcn_exp2f(s[j][r]);
                    float e1 = __builtin_amdgcn_exp2f(s[2 + j][r]);
                    ps += e0 + e1;
                    p0.e[j * 4 + r] = __float2bfloat16(e0);
                    p1.e[j * 4 + r] = __float2bfloat16(e1);
                }
            rsum[ms] += ps;
            #pragma unroll
            for (int cc = 0; cc < 4; cc++) {
                accO[ms][cc] = __builtin_amdgcn_mfma_f32_16x16x32_bf16(
                                   va[2 * cc], p0.v, accO[ms][cc], 0, 0, 0);
                accO[ms][cc] = __builtin_amdgcn_mfma_f32_16x16x32_bf16(
                                   va[2 * cc + 1], p1.v, accO[ms][cc], 0, 0, 0);
            }
        }
    }

    // ---- finalize per-wave softmax sums ----
    #pragma unroll
    for (int ms = 0; ms < 4; ms++) {
        rsum[ms] += __shfl_xor(rsum[ms], 16);
        rsum[ms] += __shfl_xor(rsum[ms], 32);
    }
    if (quad == 0) {
        #pragma unroll
        for (int ms = 0; ms < 4; ms++) lstat[mg][seg][ms * 16 + col] = rsum[ms];
    }

    // ---- four-phase combine over 4 segments, both m-groups in parallel.
    // Reducer thread t -> (mgR, c, mq): sums rows mq*4..+3 of phase p for
    // channel c; writes P in [b][c][m] layout (f32x4 along m, coalesced).
    #pragma unroll
    for (int p = 0; p < 4; p++) {
        #pragma unroll
        for (int cc = 0; cc < 4; cc++)
            *(f32x4*)(&o_lds[mg][seg][col][cc * 16 + quad * 4]) = accO[p][cc];
        __syncthreads();
        {
            const int t   = threadIdx.x;
            const int mgR = t >> 8;
            const int c   = (t >> 2) & 63;
            const int mq  = t & 3;
            f32x4 os = (f32x4){0.f, 0.f, 0.f, 0.f};
            f32x4 ls = (f32x4){0.f, 0.f, 0.f, 0.f};
            #pragma unroll
            for (int sgm = 0; sgm < NSEG; sgm++)
                #pragma unroll
                for (int j = 0; j < 4; j++) {
                    os[j] += o_lds[mgR][sgm][mq * 4 + j][c];
                    ls[j] += lstat[mgR][sgm][p * 16 + mq * 4 + j];
                }
            const int mabs = mblk * 128 + mgR * 64 + p * 16 + mq * 4;
            *(f32x4*)(Pns + ((size_t)b * C_DIM + c) * N_TOK + mabs) = os;
            if (c == 0)
                *(f32x4*)(Lns + (size_t)b * N_TOK + mabs) = ls;
        }
        __syncthreads();
    }
}

// ---------------------------------------------------------------------------
// Normalize: out = (P0+P1+P2) / (L0+L1+L2). Fully coalesced f32x4.
// grid 576 x 256 covers exactly B*C*N/4 = 147456 vectors.
// ---------------------------------------------------------------------------
__global__ __launch_bounds__(256) void norm_kernel(
    const float* __restrict__ Pb, const float* __restrict__ Lb,
    float* __restrict__ out)
{
    const size_t stride = (size_t)B_SZ * C_DIM * N_TOK;   // 589824
    const size_t f = ((size_t)blockIdx.x * 256 + threadIdx.x) * 4;
    f32x4 o = *(const f32x4*)(Pb + f) +
              *(const f32x4*)(Pb + stride + f) +
              *(const f32x4*)(Pb + 2 * stride + f);
    const int b = (int)(f / ((size_t)C_DIM * N_TOK));
    const int m = (int)(f % N_TOK);
    const size_t lf = (size_t)b * N_TOK + m;
    const size_t lstride = (size_t)B_SZ * N_TOK;          // 9216
    f32x4 l = *(const f32x4*)(Lb + lf) +
              *(const f32x4*)(Lb + lstride + lf) +
              *(const f32x4*)(Lb + 2 * lstride + lf);
    f32x4 r;
    #pragma unroll
    for (int j = 0; j < 4; j++) r[j] = o[j] / l[j];
    *(f32x4*)(out + f) = r;
}

extern "C" void kernel_launch(void* const* d_in, const int* in_sizes, int n_in,
                              void* d_out, int out_size, void* d_ws, size_t ws_size,
                              hipStream_t stream) {
    const float* x  = (const float*)d_in[0];
    const float* h  = (const float*)d_in[1];
    const float* Wq = (const float*)d_in[2];
    const float* bq = (const float*)d_in[3];
    const float* Wk = (const float*)d_in[4];
    const float* bk = (const float*)d_in[5];
    const float* Wv = (const float*)d_in[6];
    const float* bv = (const float*)d_in[7];
    float* out = (float*)d_out;

    const size_t elems = (size_t)B_SZ * N_TOK * C_DIM;   // 589824
    __hip_bfloat16* qS = (__hip_bfloat16*)d_ws;
    __hip_bfloat16* kS = qS + elems;
    __hip_bfloat16* vS = kS + elems;
    float* Pb = (float*)(vS + elems);                    // 3 x 2.36 MB
    float* Lb = Pb + NSPLIT * elems;                     // 3 x 36.9 KB

    proj_kernel<<<B_SZ * NBLK, 256, 0, stream>>>(x, h, Wq, bq, Wk, bk, Wv, bv,
                                                 qS, kS, vS);
    attn_kernel<<<B_SZ * M128BLKS * NSPLIT, 512, 0, stream>>>(qS, kS, vS, Pb, Lb);
    norm_kernel<<<576, 256, 0, stream>>>(Pb, Lb, out);
}